// Round 1
// baseline (407.219 us; speedup 1.0000x reference)
//
#include <hip/hip_runtime.h>
#include <hip/hip_bf16.h>

#define N_TOK 4096
#define CT 256

typedef __attribute__((ext_vector_type(8))) short bf16x8;
typedef __attribute__((ext_vector_type(4))) float f32x4;

__device__ __forceinline__ unsigned short f2bf(float f){
  unsigned u = __float_as_uint(f);
  u += 0x7fffu + ((u >> 16) & 1u);
  return (unsigned short)(u >> 16);
}

// ---------------------------------------------------------------------------
// Gate: conv3x3(1->32) -> ReLU -> conv1x1(32->8) -> sigmoid. One thread/pixel.
// ---------------------------------------------------------------------------
__global__ __launch_bounds__(256) void gate_kernel(
    const float* __restrict__ em, const float* __restrict__ w1,
    const float* __restrict__ b1, const float* __restrict__ w2,
    const float* __restrict__ b2, float* __restrict__ g)
{
  int n = blockIdx.x * 256 + threadIdx.x;      // 4096 pixels
  int y = n >> 6, x = n & 63;
  float e[9];
#pragma unroll
  for (int dy = 0; dy < 3; dy++)
#pragma unroll
    for (int dx = 0; dx < 3; dx++) {
      int yy = y + dy - 1, xx = x + dx - 1;
      e[dy * 3 + dx] = (yy >= 0 && yy < 64 && xx >= 0 && xx < 64)
                           ? em[yy * 64 + xx] : 0.f;
    }
  float c1[32];
#pragma unroll
  for (int oc = 0; oc < 32; oc++) {
    float a = b1[oc];
#pragma unroll
    for (int t = 0; t < 9; t++) a = fmaf(e[t], w1[oc * 9 + t], a);
    c1[oc] = fmaxf(a, 0.f);
  }
#pragma unroll
  for (int hh = 0; hh < 8; hh++) {
    float a = b2[hh];
#pragma unroll
    for (int oc = 0; oc < 32; oc++) a = fmaf(c1[oc], w2[hh * 32 + oc], a);
    g[hh * N_TOK + n] = 1.f / (1.f + __expf(-a));
  }
}

// ---------------------------------------------------------------------------
// Projection: Y[n][i] = sum_c X[c][n] * W[i][c] + bias[i], X channel-major.
// OUTMODE 0: bf16 row-major [N][256] (Q, K; scale folded in)
// OUTMODE 1: bf16 col-major [256][N] (V)
// OUTMODE 2: f32  col-major [256][N] (final output projection)
// Thread = token; 32 output channels per block.y; weights via uniform s_loads.
// ---------------------------------------------------------------------------
template <int CIN, int OUTMODE>
__global__ __launch_bounds__(256) void proj_kernel(
    const float* __restrict__ X, const float* __restrict__ W,
    const float* __restrict__ bias, float scale, void* __restrict__ Yout)
{
  int n = blockIdx.x * 256 + threadIdx.x;
  int ic = blockIdx.y * 32;
  float acc[32];
#pragma unroll
  for (int i = 0; i < 32; i++) acc[i] = bias[ic + i];
#pragma unroll 4
  for (int c = 0; c < CIN; c++) {
    float x = X[(size_t)c * N_TOK + n];
#pragma unroll
    for (int i = 0; i < 32; i++)
      acc[i] = fmaf(x, W[(size_t)(ic + i) * CIN + c], acc[i]);
  }
  if (OUTMODE == 0) {
    unsigned short* Y = (unsigned short*)Yout;
    unsigned pk[16];
#pragma unroll
    for (int i = 0; i < 16; i++) {
      unsigned short a = f2bf(acc[2 * i] * scale);
      unsigned short b = f2bf(acc[2 * i + 1] * scale);
      pk[i] = (unsigned)a | ((unsigned)b << 16);
    }
    uint4* dst = (uint4*)(Y + (size_t)n * CT + ic);
#pragma unroll
    for (int b = 0; b < 4; b++)
      dst[b] = make_uint4(pk[4 * b], pk[4 * b + 1], pk[4 * b + 2], pk[4 * b + 3]);
  } else if (OUTMODE == 1) {
    unsigned short* Y = (unsigned short*)Yout;
#pragma unroll
    for (int i = 0; i < 32; i++)
      Y[(size_t)(ic + i) * N_TOK + n] = f2bf(acc[i] * scale);
  } else {
    float* Y = (float*)Yout;
#pragma unroll
    for (int i = 0; i < 32; i++)
      Y[(size_t)(ic + i) * N_TOK + n] = acc[i] * scale;
  }
}

// ---------------------------------------------------------------------------
// Flash attention. Block = 4 waves; block -> (head, 64-row q-tile);
// wave -> 16 q-rows. Q,K row-major bf16 [N][256]; V col-major bf16 [256][N].
// S-tile via mfma_f32_16x16x32_bf16 (d=32 = one MFMA). Online softmax with
// 16-lane shfl_xor reductions. P transposed through per-wave padded LDS into
// A-fragment layout for PV. Output written transposed fp32 [256][N].
// ---------------------------------------------------------------------------
__global__ __launch_bounds__(256) void attn_kernel(
    const unsigned short* __restrict__ Qb, const unsigned short* __restrict__ Kb,
    const unsigned short* __restrict__ Vtb, const float* __restrict__ g,
    float* __restrict__ attnT)
{
  __shared__ __align__(16) unsigned short ldsp[4][16][72];  // per-wave P tiles
  const int tid = threadIdx.x;
  const int wave = tid >> 6, lane = tid & 63;
  const int lo = lane & 15, hi = lane >> 4;
  const int hh = blockIdx.x >> 6;   // head
  const int qt = blockIdx.x & 63;   // q-tile
  const int qrow0 = qt * 64 + wave * 16;

  // Q fragment: lane holds Q[qrow0+lo][hh*32 + hi*8 .. +7] (scale pre-folded)
  bf16x8 qf = *(const bf16x8*)(Qb + (size_t)(qrow0 + lo) * CT + hh * 32 + hi * 8);

  float grow[4];
#pragma unroll
  for (int r = 0; r < 4; r++) grow[r] = g[hh * N_TOK + qrow0 + hi * 4 + r];

  float m[4], lsum[4];
#pragma unroll
  for (int r = 0; r < 4; r++) { m[r] = -1e30f; lsum[r] = 0.f; }
  f32x4 acc0 = {0.f, 0.f, 0.f, 0.f}, acc1 = {0.f, 0.f, 0.f, 0.f};
  const f32x4 zero = {0.f, 0.f, 0.f, 0.f};

#pragma unroll 2
  for (int kt = 0; kt < 64; ++kt) {
    const int kbase = kt * 64;
    f32x4 sf[4];
#pragma unroll
    for (int si = 0; si < 4; si++) {
      bf16x8 kf = *(const bf16x8*)(Kb + (size_t)(kbase + si * 16 + lo) * CT +
                                   hh * 32 + hi * 8);
      sf[si] = __builtin_amdgcn_mfma_f32_16x16x32_bf16(qf, kf, zero, 0, 0, 0);
    }
    // gate + online softmax; D layout: row = hi*4+r, col = kbase + si*16 + lo
#pragma unroll
    for (int r = 0; r < 4; r++) {
      float s0 = sf[0][r] * grow[r];
      float s1 = sf[1][r] * grow[r];
      float s2 = sf[2][r] * grow[r];
      float s3 = sf[3][r] * grow[r];
      float mx = fmaxf(fmaxf(s0, s1), fmaxf(s2, s3));
      mx = fmaxf(mx, __shfl_xor(mx, 1));
      mx = fmaxf(mx, __shfl_xor(mx, 2));
      mx = fmaxf(mx, __shfl_xor(mx, 4));
      mx = fmaxf(mx, __shfl_xor(mx, 8));
      float mn = fmaxf(m[r], mx);
      float fr = __expf(m[r] - mn);
      float p0 = __expf(s0 - mn), p1 = __expf(s1 - mn);
      float p2 = __expf(s2 - mn), p3 = __expf(s3 - mn);
      float rs = p0 + p1 + p2 + p3;
      rs += __shfl_xor(rs, 1);
      rs += __shfl_xor(rs, 2);
      rs += __shfl_xor(rs, 4);
      rs += __shfl_xor(rs, 8);
      lsum[r] = lsum[r] * fr + rs;
      m[r] = mn;
      acc0[r] *= fr; acc1[r] *= fr;
      ldsp[wave][hi * 4 + r][0 * 16 + lo] = f2bf(p0);
      ldsp[wave][hi * 4 + r][1 * 16 + lo] = f2bf(p1);
      ldsp[wave][hi * 4 + r][2 * 16 + lo] = f2bf(p2);
      ldsp[wave][hi * 4 + r][3 * 16 + lo] = f2bf(p3);
    }
    // PV: per-wave-private LDS, wave-lockstep => no barrier needed
#pragma unroll
    for (int kk = 0; kk < 2; kk++) {
      bf16x8 pa = *(const bf16x8*)&ldsp[wave][lo][kk * 32 + hi * 8];
      bf16x8 vb0 = *(const bf16x8*)(Vtb + (size_t)(hh * 32 + lo) * N_TOK +
                                    kbase + kk * 32 + hi * 8);
      bf16x8 vb1 = *(const bf16x8*)(Vtb + (size_t)(hh * 32 + 16 + lo) * N_TOK +
                                    kbase + kk * 32 + hi * 8);
      acc0 = __builtin_amdgcn_mfma_f32_16x16x32_bf16(pa, vb0, acc0, 0, 0, 0);
      acc1 = __builtin_amdgcn_mfma_f32_16x16x32_bf16(pa, vb1, acc1, 0, 0, 0);
    }
  }
#pragma unroll
  for (int r = 0; r < 4; r++) {
    float inv = 1.f / lsum[r];
    acc0[r] *= inv; acc1[r] *= inv;
  }
  // out rows = q = qrow0 + hi*4 + r, cols j = jt*16 + lo; store transposed
  float4 o0 = make_float4(acc0[0], acc0[1], acc0[2], acc0[3]);
  float4 o1 = make_float4(acc1[0], acc1[1], acc1[2], acc1[3]);
  *(float4*)&attnT[(size_t)(hh * 32 + lo) * N_TOK + qrow0 + hi * 4] = o0;
  *(float4*)&attnT[(size_t)(hh * 32 + 16 + lo) * N_TOK + qrow0 + hi * 4] = o1;
}

// ---------------------------------------------------------------------------
extern "C" void kernel_launch(void* const* d_in, const int* in_sizes, int n_in,
                              void* d_out, int out_size, void* d_ws, size_t ws_size,
                              hipStream_t stream)
{
  const float* thermal = (const float*)d_in[0];
  const float* optical = (const float*)d_in[1];
  const float* em      = (const float*)d_in[2];
  const float* Wq = (const float*)d_in[3];
  const float* bq = (const float*)d_in[4];
  const float* Wk = (const float*)d_in[5];
  const float* bk = (const float*)d_in[6];
  const float* Wv = (const float*)d_in[7];
  const float* bv = (const float*)d_in[8];
  const float* w1 = (const float*)d_in[9];
  const float* b1 = (const float*)d_in[10];
  const float* w2 = (const float*)d_in[11];
  const float* b2 = (const float*)d_in[12];
  const float* Wp = (const float*)d_in[13];
  const float* bp = (const float*)d_in[14];

  char* ws = (char*)d_ws;
  unsigned short* Qb = (unsigned short*)(ws);                     // 2 MB
  unsigned short* Kb = (unsigned short*)(ws + (2u << 20));        // 2 MB
  unsigned short* Vt = (unsigned short*)(ws + (4u << 20));        // 2 MB
  float* gbuf        = (float*)(ws + (6u << 20));                 // 128 KB
  float* attnT       = (float*)(ws + (6u << 20) + (1u << 17));    // 4 MB

  const float scale = 0.17677669529663689f;  // 32^-0.5, folded into Q

  gate_kernel<<<16, 256, 0, stream>>>(em, w1, b1, w2, b2, gbuf);
  proj_kernel<256, 0><<<dim3(16, 8), 256, 0, stream>>>(thermal, Wq, bq, scale, Qb);
  proj_kernel<128, 0><<<dim3(16, 8), 256, 0, stream>>>(optical, Wk, bk, 1.0f, Kb);
  proj_kernel<128, 1><<<dim3(16, 8), 256, 0, stream>>>(optical, Wv, bv, 1.0f, Vt);
  attn_kernel<<<512, 256, 0, stream>>>(Qb, Kb, Vt, gbuf, attnT);
  proj_kernel<256, 2><<<dim3(16, 8), 256, 0, stream>>>(attnT, Wp, bp, 1.0f, d_out);
}

// Round 2
// 151.986 us; speedup vs baseline: 2.6793x; 2.6793x over previous
//
#include <hip/hip_runtime.h>
#include <hip/hip_bf16.h>

#define N_TOK 4096
#define CT 256

typedef __attribute__((ext_vector_type(8))) short bf16x8;
typedef __attribute__((ext_vector_type(16))) float f32x16;

__device__ __forceinline__ unsigned pkbf(float a, float b) {
  float2 t; t.x = a; t.y = b;
  __hip_bfloat162 h = __float22bfloat162_rn(t);
  return *reinterpret_cast<unsigned*>(&h);
}
__device__ __forceinline__ unsigned short f2bf(float f) {
  __hip_bfloat16 h = __float2bfloat16(f);
  return *reinterpret_cast<unsigned short*>(&h);
}

// ---------------------------------------------------------------------------
// Gate: conv3x3(1->32) -> ReLU -> conv1x1(32->8) -> sigmoid. One thread/pixel.
// ---------------------------------------------------------------------------
__global__ __launch_bounds__(256) void gate_kernel(
    const float* __restrict__ em, const float* __restrict__ w1,
    const float* __restrict__ b1, const float* __restrict__ w2,
    const float* __restrict__ b2, float* __restrict__ g)
{
  int n = blockIdx.x * 256 + threadIdx.x;      // 4096 pixels
  int y = n >> 6, x = n & 63;
  float e[9];
#pragma unroll
  for (int dy = 0; dy < 3; dy++)
#pragma unroll
    for (int dx = 0; dx < 3; dx++) {
      int yy = y + dy - 1, xx = x + dx - 1;
      e[dy * 3 + dx] = (yy >= 0 && yy < 64 && xx >= 0 && xx < 64)
                           ? em[yy * 64 + xx] : 0.f;
    }
  float c1[32];
#pragma unroll
  for (int oc = 0; oc < 32; oc++) {
    float a = b1[oc];
#pragma unroll
    for (int t = 0; t < 9; t++) a = fmaf(e[t], w1[oc * 9 + t], a);
    c1[oc] = fmaxf(a, 0.f);
  }
#pragma unroll
  for (int hh = 0; hh < 8; hh++) {
    float a = b2[hh];
#pragma unroll
    for (int oc = 0; oc < 32; oc++) a = fmaf(c1[oc], w2[hh * 32 + oc], a);
    g[hh * N_TOK + n] = 1.f / (1.f + __expf(-a));
  }
}

// ---------------------------------------------------------------------------
// Projection: Y[n][i] = sum_c X[c][n] * W[i][c] + bias[i], X channel-major.
// OUTMODE 0: bf16 row-major [N][CT] (Q, K; scale folded in)
// OUTMODE 1: bf16 col-major [CT][N] (V)
// OUTMODE 2: f32  col-major [CT][N] (final output projection -> d_out)
// Thread = token; 8 output channels per block.y (grid 16 x 32, 2048 waves).
// ---------------------------------------------------------------------------
template <int CIN, int OUTMODE>
__global__ __launch_bounds__(256) void proj_kernel(
    const float* __restrict__ X, const float* __restrict__ W,
    const float* __restrict__ bias, float scale, void* __restrict__ Yout)
{
  int n = blockIdx.x * 256 + threadIdx.x;
  int ic = blockIdx.y * 8;
  float acc[8];
#pragma unroll
  for (int i = 0; i < 8; i++) acc[i] = bias[ic + i];
#pragma unroll 8
  for (int c = 0; c < CIN; c++) {
    float x = X[(size_t)c * N_TOK + n];
#pragma unroll
    for (int i = 0; i < 8; i++)
      acc[i] = fmaf(x, W[(size_t)(ic + i) * CIN + c], acc[i]);
  }
  if (OUTMODE == 0) {
    unsigned pk0 = pkbf(acc[0] * scale, acc[1] * scale);
    unsigned pk1 = pkbf(acc[2] * scale, acc[3] * scale);
    unsigned pk2 = pkbf(acc[4] * scale, acc[5] * scale);
    unsigned pk3 = pkbf(acc[6] * scale, acc[7] * scale);
    *(uint4*)((unsigned short*)Yout + (size_t)n * CT + ic) =
        make_uint4(pk0, pk1, pk2, pk3);
  } else if (OUTMODE == 1) {
    unsigned short* Y = (unsigned short*)Yout;
#pragma unroll
    for (int i = 0; i < 8; i++)
      Y[(size_t)(ic + i) * N_TOK + n] = f2bf(acc[i] * scale);
  } else {
    float* Y = (float*)Yout;
#pragma unroll
    for (int i = 0; i < 8; i++)
      Y[(size_t)(ic + i) * N_TOK + n] = acc[i] * scale;
  }
}

// ---------------------------------------------------------------------------
// Flash attention, swapped-QK^T 32x32x16 structure, NO LDS, no max tracking
// (scores are O(0.5), exp cannot overflow; softmax = exp(s*g)/sum).
// Block = 4 waves, wave = 32 q-rows. Grid = (8 heads * 32 qblocks, KSPLIT).
// S^T = mfma(K, Q): lane holds P[q = lane&31][k = crow(r,hi)], crow =
// (r&3)+8*(r>>2)+4*hi. P->bf16 pairs + v_permlane32_swap_b32 builds PV
// A-fragments in-register (guide T12 recipe). Partial O (unnormalized) and
// partial row-sums written to workspace; reduce_kernel normalizes.
// ---------------------------------------------------------------------------
__global__ __launch_bounds__(256) void attn_kernel(
    const unsigned short* __restrict__ Qb, const unsigned short* __restrict__ Kb,
    const unsigned short* __restrict__ Vtb, const float* __restrict__ g,
    float* __restrict__ Op, float* __restrict__ lspart, int keys_per_split)
{
  const int tid = threadIdx.x;
  const int wave = tid >> 6, lane = tid & 63;
  const int q32 = lane & 31, hi = lane >> 5;
  const int hh = blockIdx.x >> 5;          // head
  const int qb = blockIdx.x & 31;          // 128-row q block
  const int split = blockIdx.y;
  const int qrow0 = qb * 128 + wave * 32;
  const int kbase0 = split * keys_per_split;

  // Q fragments (B-operand): lane holds Q[qrow0+q32][h*32 + slice*16 + hi*8 ..]
  const unsigned short* qptr =
      Qb + (size_t)(qrow0 + q32) * CT + hh * 32 + hi * 8;
  const bf16x8 qf0 = *(const bf16x8*)(qptr);
  const bf16x8 qf1 = *(const bf16x8*)(qptr + 16);

  const float grow = g[hh * N_TOK + qrow0 + q32];  // gate for this lane's q-row

  f32x16 acc;
#pragma unroll
  for (int i = 0; i < 16; i++) acc[i] = 0.f;
  f32x16 zero16;
#pragma unroll
  for (int i = 0; i < 16; i++) zero16[i] = 0.f;
  float lsum = 0.f;

  const unsigned short* vrow = Vtb + (size_t)(hh * 32 + q32) * N_TOK;

#pragma unroll 2
  for (int kt = 0; kt < keys_per_split; kt += 32) {
    const int kbase = kbase0 + kt;
    // K fragments (A-operand): lane holds K[kbase+q32][slice*16 + hi*8 ..]
    const unsigned short* kptr =
        Kb + (size_t)(kbase + q32) * CT + hh * 32 + hi * 8;
    bf16x8 kf0 = *(const bf16x8*)(kptr);
    bf16x8 kf1 = *(const bf16x8*)(kptr + 16);
    // V fragments (B-operand): lane holds V^T[vj=q32][kbase + ks*16 + hi*8 ..]
    bf16x8 vb0 = *(const bf16x8*)(vrow + kbase + hi * 8);
    bf16x8 vb1 = *(const bf16x8*)(vrow + kbase + 16 + hi * 8);

    // S^T tile: rows k (crow), cols q (lane&31); d=32 = 2 chained MFMAs
    f32x16 s = __builtin_amdgcn_mfma_f32_32x32x16_bf16(kf0, qf0, zero16, 0, 0, 0);
    s = __builtin_amdgcn_mfma_f32_32x32x16_bf16(kf1, qf1, s, 0, 0, 0);

    float p[16];
#pragma unroll
    for (int r = 0; r < 16; r++) p[r] = __expf(s[r] * grow);

    lsum += (((p[0] + p[1]) + (p[2] + p[3])) + ((p[4] + p[5]) + (p[6] + p[7]))) +
            (((p[8] + p[9]) + (p[10] + p[11])) + ((p[12] + p[13]) + (p[14] + p[15])));

    // P -> bf16 A-fragments via pack + permlane32_swap (one swap fills w0&w2)
    unsigned a0 = pkbf(p[0], p[1]),  a1 = pkbf(p[2], p[3]);
    unsigned b0 = pkbf(p[4], p[5]),  b1 = pkbf(p[6], p[7]);
    unsigned c0 = pkbf(p[8], p[9]),  c1 = pkbf(p[10], p[11]);
    unsigned d0 = pkbf(p[12], p[13]), d1 = pkbf(p[14], p[15]);
    asm("v_permlane32_swap_b32 %0, %1" : "+v"(a0), "+v"(b0));
    asm("v_permlane32_swap_b32 %0, %1" : "+v"(a1), "+v"(b1));
    asm("v_permlane32_swap_b32 %0, %1" : "+v"(c0), "+v"(d0));
    asm("v_permlane32_swap_b32 %0, %1" : "+v"(c1), "+v"(d1));
    union { unsigned w[4]; bf16x8 v; } u0, u1;
    u0.w[0] = a0; u0.w[1] = a1; u0.w[2] = b0; u0.w[3] = b1;  // k 0..15
    u1.w[0] = c0; u1.w[1] = c1; u1.w[2] = d0; u1.w[3] = d1;  // k 16..31

    acc = __builtin_amdgcn_mfma_f32_32x32x16_bf16(u0.v, vb0, acc, 0, 0, 0);
    acc = __builtin_amdgcn_mfma_f32_32x32x16_bf16(u1.v, vb1, acc, 0, 0, 0);
  }

  // total row-sum for this lane's q (partner lane holds other 16 k of each tile)
  float lt = lsum + __shfl_xor(lsum, 32);
  if (hi == 0)
    lspart[((size_t)split * 8 + hh) * N_TOK + qrow0 + q32] = lt;

  // acc[r] = O_unnorm[q = qrow0 + crow(r,hi)][vj = q32]; store c-major
  float* obase = Op + ((size_t)split * 256 + hh * 32 + q32) * N_TOK + qrow0;
#pragma unroll
  for (int t = 0; t < 4; t++) {
    float4 o = make_float4(acc[4 * t], acc[4 * t + 1], acc[4 * t + 2], acc[4 * t + 3]);
    *(float4*)(obase + 8 * t + 4 * hi) = o;
  }
}

// ---------------------------------------------------------------------------
// Combine K-splits + normalize: attnT[c][n] = sum_s Op[s][c][n] / sum_s ls[s][hh][n]
// (for ksplit==1, Op may alias attnT: pure elementwise, safe.)
// ---------------------------------------------------------------------------
__global__ __launch_bounds__(256) void reduce_kernel(
    const float* __restrict__ Op, const float* __restrict__ ls,
    float* __restrict__ attnT, int ksplit)
{
  int idx = blockIdx.x * 256 + threadIdx.x;   // 256*4096
  int c = idx >> 12, n = idx & 4095;
  int hh = c >> 5;
  float o = 0.f, l = 0.f;
  for (int s = 0; s < ksplit; s++) {
    o += Op[((size_t)s * 256 + c) * N_TOK + n];
    l += ls[((size_t)s * 8 + hh) * N_TOK + n];
  }
  attnT[(size_t)c * N_TOK + n] = o / l;
}

// ---------------------------------------------------------------------------
extern "C" void kernel_launch(void* const* d_in, const int* in_sizes, int n_in,
                              void* d_out, int out_size, void* d_ws, size_t ws_size,
                              hipStream_t stream)
{
  const float* thermal = (const float*)d_in[0];
  const float* optical = (const float*)d_in[1];
  const float* em      = (const float*)d_in[2];
  const float* Wq = (const float*)d_in[3];
  const float* bq = (const float*)d_in[4];
  const float* Wk = (const float*)d_in[5];
  const float* bk = (const float*)d_in[6];
  const float* Wv = (const float*)d_in[7];
  const float* bv = (const float*)d_in[8];
  const float* w1 = (const float*)d_in[9];
  const float* b1 = (const float*)d_in[10];
  const float* w2 = (const float*)d_in[11];
  const float* b2 = (const float*)d_in[12];
  const float* Wp = (const float*)d_in[13];
  const float* bp = (const float*)d_in[14];

  char* ws = (char*)d_ws;
  const size_t MB = 1u << 20;
  unsigned short* Qb = (unsigned short*)(ws);            // 2 MB
  unsigned short* Kb = (unsigned short*)(ws + 2 * MB);   // 2 MB
  unsigned short* Vt = (unsigned short*)(ws + 4 * MB);   // 2 MB
  float* gbuf        = (float*)(ws + 6 * MB);            // 128 KB

  // choose K-split by available workspace
  const size_t lsoff = 6 * MB + (128u << 10);
  int ksplit;
  size_t need4 = lsoff + 4 * (128u << 10) + 4 * MB + 16 * MB;
  size_t need2 = lsoff + 2 * (128u << 10) + 4 * MB + 8 * MB;
  if (ws_size >= need4) ksplit = 4;
  else if (ws_size >= need2) ksplit = 2;
  else ksplit = 1;

  float* lsp   = (float*)(ws + lsoff);
  float* attnT = (float*)(ws + lsoff + (size_t)ksplit * (128u << 10));
  float* Op    = (ksplit == 1) ? attnT
               : (float*)((char*)attnT + 4 * MB);

  const float scale = 0.17677669529663689f;  // 32^-0.5, folded into Q

  gate_kernel<<<16, 256, 0, stream>>>(em, w1, b1, w2, b2, gbuf);
  proj_kernel<256, 0><<<dim3(16, 32), 256, 0, stream>>>(thermal, Wq, bq, scale, Qb);
  proj_kernel<128, 0><<<dim3(16, 32), 256, 0, stream>>>(optical, Wk, bk, 1.0f, Kb);
  proj_kernel<128, 1><<<dim3(16, 32), 256, 0, stream>>>(optical, Wv, bv, 1.0f, Vt);
  attn_kernel<<<dim3(256, ksplit), 256, 0, stream>>>(Qb, Kb, Vt, gbuf, Op, lsp,
                                                     N_TOK / ksplit);
  reduce_kernel<<<4096, 256, 0, stream>>>(Op, lsp, attnT, ksplit);
  proj_kernel<256, 2><<<dim3(16, 32), 256, 0, stream>>>(attnT, Wp, bp, 1.0f, d_out);
}

// Round 3
// 114.596 us; speedup vs baseline: 3.5535x; 1.3263x over previous
//
#include <hip/hip_runtime.h>
#include <hip/hip_bf16.h>

#define N_TOK 4096
#define CT 256

typedef __attribute__((ext_vector_type(8))) short bf16x8;
typedef __attribute__((ext_vector_type(16))) float f32x16;

__device__ __forceinline__ unsigned pkbf(float a, float b) {
  float2 t; t.x = a; t.y = b;
  __hip_bfloat162 h = __float22bfloat162_rn(t);
  return *reinterpret_cast<unsigned*>(&h);
}
__device__ __forceinline__ unsigned short f2bf(float f) {
  __hip_bfloat16 h = __float2bfloat16(f);
  return *reinterpret_cast<unsigned short*>(&h);
}
__device__ __forceinline__ float bf2f(unsigned short u) {
  return __uint_as_float(((unsigned)u) << 16);
}

// ---------------------------------------------------------------------------
// Gate: conv3x3(1->32) -> ReLU -> conv1x1(32->8) -> sigmoid. One thread/pixel.
// ---------------------------------------------------------------------------
__global__ __launch_bounds__(256) void gate_kernel(
    const float* __restrict__ em, const float* __restrict__ w1,
    const float* __restrict__ b1, const float* __restrict__ w2,
    const float* __restrict__ b2, float* __restrict__ g)
{
  int n = blockIdx.x * 256 + threadIdx.x;
  int y = n >> 6, x = n & 63;
  float e[9];
#pragma unroll
  for (int dy = 0; dy < 3; dy++)
#pragma unroll
    for (int dx = 0; dx < 3; dx++) {
      int yy = y + dy - 1, xx = x + dx - 1;
      e[dy * 3 + dx] = (yy >= 0 && yy < 64 && xx >= 0 && xx < 64)
                           ? em[yy * 64 + xx] : 0.f;
    }
  float c1[32];
#pragma unroll
  for (int oc = 0; oc < 32; oc++) {
    float a = b1[oc];
#pragma unroll
    for (int t = 0; t < 9; t++) a = fmaf(e[t], w1[oc * 9 + t], a);
    c1[oc] = fmaxf(a, 0.f);
  }
#pragma unroll
  for (int hh = 0; hh < 8; hh++) {
    float a = b2[hh];
#pragma unroll
    for (int oc = 0; oc < 32; oc++) a = fmaf(c1[oc], w2[hh * 32 + oc], a);
    g[hh * N_TOK + n] = 1.f / (1.f + __expf(-a));
  }
}

// ---------------------------------------------------------------------------
// Weight convert: all 4 matrices f32 -> bf16 into one contiguous buffer.
// elem offsets: Wq 0, Wk 65536, Wv 98304, Wp 131072 (total 196608).
// ---------------------------------------------------------------------------
__global__ __launch_bounds__(256) void wcvt_kernel(
    const float* __restrict__ Wq, const float* __restrict__ Wk,
    const float* __restrict__ Wv, const float* __restrict__ Wp,
    unsigned short* __restrict__ dst)
{
  int i = blockIdx.x * 256 + threadIdx.x;
  const float* src; int off;
  if (i < 65536)       { src = Wq; off = 0; }
  else if (i < 98304)  { src = Wk; off = 65536; }
  else if (i < 131072) { src = Wv; off = 98304; }
  else                 { src = Wp; off = 131072; }
  dst[i] = f2bf(src[i - off]);
}

// ---------------------------------------------------------------------------
// X convert+transpose: f32 [CIN][4096] -> bf16 [4096][CIN] via LDS tile.
// Block = 64 tokens.
// ---------------------------------------------------------------------------
template <int CIN>
__global__ __launch_bounds__(256) void xcvt_kernel(
    const float* __restrict__ X, unsigned short* __restrict__ Xb)
{
  __shared__ unsigned short tile[64][CIN + 8];
  const int tid = threadIdx.x;
  const int n0 = blockIdx.x * 64;
  const int nl = tid & 63;
  const int cw = (tid >> 6) * 4;
#pragma unroll
  for (int c0 = 0; c0 < CIN; c0 += 16) {
    int c = c0 + cw;
    float x0 = X[(size_t)(c + 0) * N_TOK + n0 + nl];
    float x1 = X[(size_t)(c + 1) * N_TOK + n0 + nl];
    float x2 = X[(size_t)(c + 2) * N_TOK + n0 + nl];
    float x3 = X[(size_t)(c + 3) * N_TOK + n0 + nl];
    uint2 w; w.x = pkbf(x0, x1); w.y = pkbf(x2, x3);
    *(uint2*)&tile[nl][c] = w;
  }
  __syncthreads();
  const int n = tid >> 2, q = tid & 3;
  const int cb = q * (CIN / 4);
#pragma unroll
  for (int j = 0; j < CIN / 4; j += 4) {
    uint2 w = *(const uint2*)&tile[n][cb + j];
    *(uint2*)(Xb + (size_t)(n0 + n) * CIN + cb + j) = w;
  }
}

// ---------------------------------------------------------------------------
// MFMA GEMM: Y[token][out] = Xb[token][CIN] @ Wb[out][CIN]^T + bias.
// Wave = 32 tok x 32 out tile; block = 4 waves (128 tok); grid (32, 8).
// OUTMODE 0: bf16 token-major, epilogue * (attn_scale * gate[head][tok]) (Q)
// OUTMODE 1: bf16 token-major (K)
// OUTMODE 2: bf16 col-major [out][4096] (V^T)
// OUTMODE 3: f32 col-major [out][4096] (final output -> d_out)
// ---------------------------------------------------------------------------
template <int CIN, int OUTMODE>
__global__ __launch_bounds__(256) void gemm_kernel(
    const unsigned short* __restrict__ Xb, const unsigned short* __restrict__ Wb,
    const float* __restrict__ bias, const float* __restrict__ g,
    void* __restrict__ Yout)
{
  __shared__ float ldsT[4][32][33];
  const int tid = threadIdx.x;
  const int wave = tid >> 6, lane = tid & 63;
  const int l31 = lane & 31, hi = lane >> 5;
  const int n0 = blockIdx.x * 128 + wave * 32;
  const int o0 = blockIdx.y * 32;

  const unsigned short* xp = Xb + (size_t)(n0 + l31) * CIN + hi * 8;
  const unsigned short* wp = Wb + (size_t)(o0 + l31) * CIN + hi * 8;

  f32x16 accE, accO;
#pragma unroll
  for (int i = 0; i < 16; i++) { accE[i] = 0.f; accO[i] = 0.f; }
#pragma unroll
  for (int c = 0; c < CIN; c += 32) {
    bf16x8 a0 = *(const bf16x8*)(xp + c);
    bf16x8 b0 = *(const bf16x8*)(wp + c);
    bf16x8 a1 = *(const bf16x8*)(xp + c + 16);
    bf16x8 b1 = *(const bf16x8*)(wp + c + 16);
    accE = __builtin_amdgcn_mfma_f32_32x32x16_bf16(a0, b0, accE, 0, 0, 0);
    accO = __builtin_amdgcn_mfma_f32_32x32x16_bf16(a1, b1, accO, 0, 0, 0);
  }
  const float bo = bias[o0 + l31];
  float val[16];
#pragma unroll
  for (int r = 0; r < 16; r++) val[r] = accE[r] + accO[r] + bo;

  if (OUTMODE == 0) {
    const int head = blockIdx.y;            // 32-ch tiles == heads
#pragma unroll
    for (int r = 0; r < 16; r++) {
      int t = n0 + (r & 3) + 8 * (r >> 2) + 4 * hi;
      val[r] *= 0.17677669529663689f * g[head * N_TOK + t];
    }
  }

  if (OUTMODE == 0 || OUTMODE == 1) {
    // transpose via per-wave LDS tile -> token-major bf16 rows
#pragma unroll
    for (int r = 0; r < 16; r++)
      ldsT[wave][(r & 3) + 8 * (r >> 2) + 4 * hi][l31] = val[r];
    unsigned short* Y = (unsigned short*)Yout;
    unsigned pk[8];
#pragma unroll
    for (int i = 0; i < 8; i++)
      pk[i] = pkbf(ldsT[wave][l31][16 * hi + 2 * i],
                   ldsT[wave][l31][16 * hi + 2 * i + 1]);
    unsigned short* dst = Y + (size_t)(n0 + l31) * CT + o0 + 16 * hi;
    *(uint4*)dst = make_uint4(pk[0], pk[1], pk[2], pk[3]);
    *(uint4*)(dst + 8) = make_uint4(pk[4], pk[5], pk[6], pk[7]);
  } else if (OUTMODE == 2) {
    unsigned short* Y = (unsigned short*)Yout;
#pragma unroll
    for (int rr = 0; rr < 4; rr++) {
      uint2 w;
      w.x = pkbf(val[4 * rr], val[4 * rr + 1]);
      w.y = pkbf(val[4 * rr + 2], val[4 * rr + 3]);
      *(uint2*)(Y + (size_t)(o0 + l31) * N_TOK + n0 + 8 * rr + 4 * hi) = w;
    }
  } else {
    float* Y = (float*)Yout;
#pragma unroll
    for (int rr = 0; rr < 4; rr++) {
      float4 w = make_float4(val[4 * rr], val[4 * rr + 1],
                             val[4 * rr + 2], val[4 * rr + 3]);
      *(float4*)(Y + (size_t)(o0 + l31) * N_TOK + n0 + 8 * rr + 4 * hi) = w;
    }
  }
}

// ---------------------------------------------------------------------------
// Flash attention, swapped-QK^T 32x32x16, no LDS in main loop, no max
// tracking (gated scores are O(1); exp cannot overflow). Gate & scale are
// pre-folded into Qb. Per-tile VALU = 16 exp + sum + 8 cvtpk + 4 permlane.
// Epilogue: per-wave LDS transpose -> bf16 token-major partial O.
// ---------------------------------------------------------------------------
__global__ __launch_bounds__(256, 6) void attn_kernel(
    const unsigned short* __restrict__ Qb, const unsigned short* __restrict__ Kb,
    const unsigned short* __restrict__ Vtb,
    unsigned short* __restrict__ Ob, float* __restrict__ ls, int keys_per_split)
{
  __shared__ float ldsT[4][32][33];
  const int tid = threadIdx.x;
  const int wave = tid >> 6, lane = tid & 63;
  const int l31 = lane & 31, hi = lane >> 5;
  const int hh = blockIdx.x >> 5;
  const int qb = blockIdx.x & 31;
  const int split = blockIdx.y;
  const int qrow0 = qb * 128 + wave * 32;
  const int kbase0 = split * keys_per_split;

  const unsigned short* qptr = Qb + (size_t)(qrow0 + l31) * CT + hh * 32 + hi * 8;
  const bf16x8 qf0 = *(const bf16x8*)(qptr);
  const bf16x8 qf1 = *(const bf16x8*)(qptr + 16);

  f32x16 acc, zero16;
#pragma unroll
  for (int i = 0; i < 16; i++) { acc[i] = 0.f; zero16[i] = 0.f; }
  float lsum = 0.f;

  const unsigned short* vrow = Vtb + (size_t)(hh * 32 + l31) * N_TOK;

#pragma unroll 2
  for (int kt = 0; kt < keys_per_split; kt += 32) {
    const int kbase = kbase0 + kt;
    const unsigned short* kptr =
        Kb + (size_t)(kbase + l31) * CT + hh * 32 + hi * 8;
    bf16x8 kf0 = *(const bf16x8*)(kptr);
    bf16x8 kf1 = *(const bf16x8*)(kptr + 16);
    bf16x8 vb0 = *(const bf16x8*)(vrow + kbase + hi * 8);
    bf16x8 vb1 = *(const bf16x8*)(vrow + kbase + 16 + hi * 8);

    f32x16 s = __builtin_amdgcn_mfma_f32_32x32x16_bf16(kf0, qf0, zero16, 0, 0, 0);
    s = __builtin_amdgcn_mfma_f32_32x32x16_bf16(kf1, qf1, s, 0, 0, 0);

    float p[16];
#pragma unroll
    for (int r = 0; r < 16; r++) p[r] = __expf(s[r]);

    lsum += (((p[0] + p[1]) + (p[2] + p[3])) + ((p[4] + p[5]) + (p[6] + p[7]))) +
            (((p[8] + p[9]) + (p[10] + p[11])) + ((p[12] + p[13]) + (p[14] + p[15])));

    unsigned a0 = pkbf(p[0], p[1]),   a1 = pkbf(p[2], p[3]);
    unsigned b0 = pkbf(p[4], p[5]),   b1 = pkbf(p[6], p[7]);
    unsigned c0 = pkbf(p[8], p[9]),   c1 = pkbf(p[10], p[11]);
    unsigned d0 = pkbf(p[12], p[13]), d1 = pkbf(p[14], p[15]);
    asm("v_permlane32_swap_b32 %0, %1" : "+v"(a0), "+v"(b0));
    asm("v_permlane32_swap_b32 %0, %1" : "+v"(a1), "+v"(b1));
    asm("v_permlane32_swap_b32 %0, %1" : "+v"(c0), "+v"(d0));
    asm("v_permlane32_swap_b32 %0, %1" : "+v"(c1), "+v"(d1));
    union { unsigned w[4]; bf16x8 v; } u0, u1;
    u0.w[0] = a0; u0.w[1] = a1; u0.w[2] = b0; u0.w[3] = b1;
    u1.w[0] = c0; u1.w[1] = c1; u1.w[2] = d0; u1.w[3] = d1;

    acc = __builtin_amdgcn_mfma_f32_32x32x16_bf16(u0.v, vb0, acc, 0, 0, 0);
    acc = __builtin_amdgcn_mfma_f32_32x32x16_bf16(u1.v, vb1, acc, 0, 0, 0);
  }

  float lt = lsum + __shfl_xor(lsum, 32);
  if (hi == 0)
    ls[((size_t)split * 8 + hh) * N_TOK + qrow0 + l31] = lt;

  // epilogue: acc[r] = O[q = qrow0+crow(r,hi)][vj = l31]; transpose to
  // token-major bf16 rows via per-wave LDS (wave-lockstep, no barrier).
#pragma unroll
  for (int r = 0; r < 16; r++)
    ldsT[wave][(r & 3) + 8 * (r >> 2) + 4 * hi][l31] = acc[r];
  unsigned pk[8];
#pragma unroll
  for (int i = 0; i < 8; i++)
    pk[i] = pkbf(ldsT[wave][l31][16 * hi + 2 * i],
                 ldsT[wave][l31][16 * hi + 2 * i + 1]);
  unsigned short* dst =
      Ob + ((size_t)split * N_TOK + qrow0 + l31) * CT + hh * 32 + 16 * hi;
  *(uint4*)dst = make_uint4(pk[0], pk[1], pk[2], pk[3]);
  *(uint4*)(dst + 8) = make_uint4(pk[4], pk[5], pk[6], pk[7]);
}

// ---------------------------------------------------------------------------
// Combine splits + normalize -> Ab[n][c] bf16 (input of out-projection GEMM).
// Thread = 8 channels of one token (16B loads/stores).
// ---------------------------------------------------------------------------
__global__ __launch_bounds__(256) void reduce_kernel(
    const unsigned short* __restrict__ Ob, const float* __restrict__ ls,
    unsigned short* __restrict__ Ab, int ksplit)
{
  int gid = blockIdx.x * 256 + threadIdx.x;   // 131072
  int n = gid >> 5, c0 = (gid & 31) * 8;
  int head = c0 >> 5;
  float o[8];
#pragma unroll
  for (int i = 0; i < 8; i++) o[i] = 0.f;
  float l = 0.f;
  for (int s = 0; s < ksplit; s++) {
    const unsigned short* src = Ob + ((size_t)s * N_TOK + n) * CT + c0;
    uint4 raw = *(const uint4*)src;
    unsigned w[4] = {raw.x, raw.y, raw.z, raw.w};
#pragma unroll
    for (int i = 0; i < 4; i++) {
      o[2 * i]     += __uint_as_float(w[i] << 16);
      o[2 * i + 1] += __uint_as_float(w[i] & 0xffff0000u);
    }
    l += ls[((size_t)s * 8 + head) * N_TOK + n];
  }
  float inv = 1.f / l;
  unsigned pk[4];
#pragma unroll
  for (int i = 0; i < 4; i++)
    pk[i] = pkbf(o[2 * i] * inv, o[2 * i + 1] * inv);
  *(uint4*)(Ab + (size_t)n * CT + c0) = make_uint4(pk[0], pk[1], pk[2], pk[3]);
}

// ---------------------------------------------------------------------------
extern "C" void kernel_launch(void* const* d_in, const int* in_sizes, int n_in,
                              void* d_out, int out_size, void* d_ws, size_t ws_size,
                              hipStream_t stream)
{
  const float* thermal = (const float*)d_in[0];
  const float* optical = (const float*)d_in[1];
  const float* em      = (const float*)d_in[2];
  const float* Wq = (const float*)d_in[3];
  const float* bq = (const float*)d_in[4];
  const float* Wk = (const float*)d_in[5];
  const float* bk = (const float*)d_in[6];
  const float* Wv = (const float*)d_in[7];
  const float* bv = (const float*)d_in[8];
  const float* w1 = (const float*)d_in[9];
  const float* b1 = (const float*)d_in[10];
  const float* w2 = (const float*)d_in[11];
  const float* b2 = (const float*)d_in[12];
  const float* Wp = (const float*)d_in[13];
  const float* bp = (const float*)d_in[14];

  char* ws = (char*)d_ws;
  const size_t MB = 1u << 20;
  unsigned short* Xbt = (unsigned short*)(ws);             // [4096][256] 2MB
  unsigned short* Xbo = (unsigned short*)(ws + 2 * MB);    // [4096][128] 1MB
  unsigned short* Wall = (unsigned short*)(ws + 3 * MB);   // 384KB
  unsigned short* Wqb = Wall;
  unsigned short* Wkb = Wall + 65536;
  unsigned short* Wvb = Wall + 98304;
  unsigned short* Wpb = Wall + 131072;
  float* gbuf = (float*)(ws + 3 * MB + 512 * 1024);        // 128KB
  unsigned short* Qb = (unsigned short*)(ws + 4 * MB);     // 2MB
  unsigned short* Kb = (unsigned short*)(ws + 6 * MB);     // 2MB
  unsigned short* Vt = (unsigned short*)(ws + 8 * MB);     // 2MB
  unsigned short* Ab = (unsigned short*)(ws + 10 * MB);    // 2MB
  float* lsp = (float*)(ws + 12 * MB);                     // ksplit*128KB
  unsigned short* Ob = (unsigned short*)(ws + 13 * MB);    // ksplit*2MB

  const int ksplit = (ws_size >= 29 * MB) ? 8 : 4;

  gate_kernel<<<16, 256, 0, stream>>>(em, w1, b1, w2, b2, gbuf);
  wcvt_kernel<<<768, 256, 0, stream>>>(Wq, Wk, Wv, Wp, Wall);
  xcvt_kernel<256><<<64, 256, 0, stream>>>(thermal, Xbt);
  xcvt_kernel<128><<<64, 256, 0, stream>>>(optical, Xbo);

  gemm_kernel<256, 0><<<dim3(32, 8), 256, 0, stream>>>(Xbt, Wqb, bq, gbuf, Qb);
  gemm_kernel<128, 1><<<dim3(32, 8), 256, 0, stream>>>(Xbo, Wkb, bk, nullptr, Kb);
  gemm_kernel<128, 2><<<dim3(32, 8), 256, 0, stream>>>(Xbo, Wvb, bv, nullptr, Vt);

  attn_kernel<<<dim3(256, ksplit), 256, 0, stream>>>(Qb, Kb, Vt, Ob, lsp,
                                                     N_TOK / ksplit);
  reduce_kernel<<<512, 256, 0, stream>>>(Ob, lsp, Ab, ksplit);

  gemm_kernel<256, 3><<<dim3(32, 8), 256, 0, stream>>>(Ab, Wpb, bp, nullptr, d_out);
}

// Round 5
// 70.424 us; speedup vs baseline: 5.7824x; 1.6272x over previous
//
#include <hip/hip_runtime.h>
#include <hip/hip_bf16.h>

#define N_TOK 4096
#define CT 256

typedef __attribute__((ext_vector_type(8))) short bf16x8;
typedef __attribute__((ext_vector_type(16))) float f32x16;

__device__ __forceinline__ unsigned pkbf(float a, float b) {
  float2 t; t.x = a; t.y = b;
  __hip_bfloat162 h = __float22bfloat162_rn(t);
  return *reinterpret_cast<unsigned*>(&h);
}

#if __has_builtin(__builtin_amdgcn_exp2f)
__device__ __forceinline__ float fexp2(float x) { return __builtin_amdgcn_exp2f(x); }
#else
__device__ __forceinline__ float fexp2(float x) { return exp2f(x); }
#endif

// ---------------------------------------------------------------------------
// prep: [0,128) X convert+transpose (thermal/optical), [128,224) weight cvt,
// [224,240) emissivity gate.
// ---------------------------------------------------------------------------
__global__ __launch_bounds__(256) void prep_kernel(
    const float* __restrict__ thermal, const float* __restrict__ optical,
    const float* __restrict__ Wq, const float* __restrict__ Wk,
    const float* __restrict__ Wv, const float* __restrict__ Wp,
    const float* __restrict__ em, const float* __restrict__ w1,
    const float* __restrict__ b1, const float* __restrict__ w2,
    const float* __restrict__ b2,
    unsigned short* __restrict__ Xbt, unsigned short* __restrict__ Xbo,
    unsigned short* __restrict__ Wall, float* __restrict__ g)
{
  __shared__ unsigned short tile[64][264];
  const int bx = blockIdx.x, tid = threadIdx.x;
  if (bx < 128) {
    const bool th = (bx < 64);
    const float* X = th ? thermal : optical;
    unsigned short* Xb = th ? Xbt : Xbo;
    const int CIN = th ? 256 : 128;
    const int n0 = (th ? bx : bx - 64) * 64;
    const int nl = tid & 63;
    const int cw = (tid >> 6) * 4;
    for (int c0 = 0; c0 < CIN; c0 += 16) {
      int c = c0 + cw;
      float x0 = X[(size_t)(c + 0) * N_TOK + n0 + nl];
      float x1 = X[(size_t)(c + 1) * N_TOK + n0 + nl];
      float x2 = X[(size_t)(c + 2) * N_TOK + n0 + nl];
      float x3 = X[(size_t)(c + 3) * N_TOK + n0 + nl];
      uint2 w; w.x = pkbf(x0, x1); w.y = pkbf(x2, x3);
      *(uint2*)&tile[nl][c] = w;
    }
    __syncthreads();
    const int n = tid >> 2, q = tid & 3;
    const int cb = q * (CIN / 4);
    for (int j = 0; j < CIN / 4; j += 4)
      *(uint2*)(Xb + (size_t)(n0 + n) * CIN + cb + j) = *(const uint2*)&tile[n][cb + j];
  } else if (bx < 224) {
    int i = (bx - 128) * 2048 + tid * 8;   // 196608 total
    const float* src; int off;
    if (i < 65536)       { src = Wq; off = 0; }
    else if (i < 98304)  { src = Wk; off = 65536; }
    else if (i < 131072) { src = Wv; off = 98304; }
    else                 { src = Wp; off = 131072; }
    float4 f0 = *(const float4*)(src + (i - off));
    float4 f1 = *(const float4*)(src + (i - off) + 4);
    uint4 o;
    o.x = pkbf(f0.x, f0.y); o.y = pkbf(f0.z, f0.w);
    o.z = pkbf(f1.x, f1.y); o.w = pkbf(f1.z, f1.w);
    *(uint4*)(Wall + i) = o;
  } else {
    int n = (bx - 224) * 256 + tid;
    int y = n >> 6, x = n & 63;
    float e[9];
#pragma unroll
    for (int dy = 0; dy < 3; dy++)
#pragma unroll
      for (int dx = 0; dx < 3; dx++) {
        int yy = y + dy - 1, xx = x + dx - 1;
        e[dy * 3 + dx] = (yy >= 0 && yy < 64 && xx >= 0 && xx < 64)
                             ? em[yy * 64 + xx] : 0.f;
      }
    float c1[32];
#pragma unroll
    for (int oc = 0; oc < 32; oc++) {
      float a = b1[oc];
#pragma unroll
      for (int t = 0; t < 9; t++) a = fmaf(e[t], w1[oc * 9 + t], a);
      c1[oc] = fmaxf(a, 0.f);
    }
#pragma unroll
    for (int hh = 0; hh < 8; hh++) {
      float a = b2[hh];
#pragma unroll
      for (int oc = 0; oc < 32; oc++) a = fmaf(c1[oc], w2[hh * 32 + oc], a);
      g[hh * N_TOK + n] = 1.f / (1.f + __expf(-a));
    }
  }
}

// ---------------------------------------------------------------------------
// Shared 32tok x 32out MFMA tile.
// ---------------------------------------------------------------------------
template <int CIN>
__device__ __forceinline__ void gemm_tile(
    const unsigned short* __restrict__ xp, const unsigned short* __restrict__ wp,
    f32x16& accE, f32x16& accO)
{
#pragma unroll
  for (int c = 0; c < CIN; c += 32) {
    bf16x8 a0 = *(const bf16x8*)(xp + c);
    bf16x8 b0 = *(const bf16x8*)(wp + c);
    bf16x8 a1 = *(const bf16x8*)(xp + c + 16);
    bf16x8 b1 = *(const bf16x8*)(wp + c + 16);
    accE = __builtin_amdgcn_mfma_f32_32x32x16_bf16(a0, b0, accE, 0, 0, 0);
    accO = __builtin_amdgcn_mfma_f32_32x32x16_bf16(a1, b1, accO, 0, 0, 0);
  }
}

// ---------------------------------------------------------------------------
// Fused QKV projection. grid (32, 24): y 0-7 Q, 8-15 K, 16-23 V (head = y&7).
// Q/K -> per-head token-major [8][4096][32] bf16 (Q folds gate*scale*log2e).
// V  -> PV B-fragment layout [8][256 ktiles][32 ch][16 tok] bf16.
// ---------------------------------------------------------------------------
__global__ __launch_bounds__(256) void qkv_kernel(
    const unsigned short* __restrict__ Xbt, const unsigned short* __restrict__ Xbo,
    const unsigned short* __restrict__ Wall,
    const float* __restrict__ bq, const float* __restrict__ bk,
    const float* __restrict__ bv, const float* __restrict__ g,
    unsigned short* __restrict__ Qh, unsigned short* __restrict__ Kh,
    unsigned short* __restrict__ Vf)
{
  __shared__ float ldsT[4][32][33];
  const int tid = threadIdx.x;
  const int wave = tid >> 6, lane = tid & 63;
  const int l31 = lane & 31, hi = lane >> 5;
  const int y = blockIdx.y;
  const int head = y & 7;
  const int n0 = blockIdx.x * 128 + wave * 32;

  f32x16 accE, accO;
#pragma unroll
  for (int i = 0; i < 16; i++) { accE[i] = 0.f; accO[i] = 0.f; }
  float bo;
  if (y < 8) {
    gemm_tile<256>(Xbt + (size_t)(n0 + l31) * 256 + hi * 8,
                   Wall + (size_t)(head * 32 + l31) * 256 + hi * 8, accE, accO);
    bo = bq[head * 32 + l31];
  } else if (y < 16) {
    gemm_tile<128>(Xbo + (size_t)(n0 + l31) * 128 + hi * 8,
                   Wall + 65536 + (size_t)(head * 32 + l31) * 128 + hi * 8, accE, accO);
    bo = bk[head * 32 + l31];
  } else {
    gemm_tile<128>(Xbo + (size_t)(n0 + l31) * 128 + hi * 8,
                   Wall + 98304 + (size_t)(head * 32 + l31) * 128 + hi * 8, accE, accO);
    bo = bv[head * 32 + l31];
  }
  float val[16];
#pragma unroll
  for (int r = 0; r < 16; r++) val[r] = accE[r] + accO[r] + bo;

  if (y < 8) {
    const float QSC = 0.17677669529663689f * 1.4426950408889634f;
#pragma unroll
    for (int r = 0; r < 16; r++) {
      int t = n0 + (r & 3) + 8 * (r >> 2) + 4 * hi;
      val[r] *= QSC * g[head * N_TOK + t];
    }
  }

  // acc layout: val[r] = Y[token n0+crow(r,hi)][ch head*32+l31]; transpose.
#pragma unroll
  for (int r = 0; r < 16; r++)
    ldsT[wave][(r & 3) + 8 * (r >> 2) + 4 * hi][l31] = val[r];

  if (y < 16) {
    // token-major rows of 32 ch: lane holds ch 16hi..16hi+15 of token n0+l31
    unsigned pk[8];
#pragma unroll
    for (int i = 0; i < 8; i++)
      pk[i] = pkbf(ldsT[wave][l31][16 * hi + 2 * i],
                   ldsT[wave][l31][16 * hi + 2 * i + 1]);
    unsigned short* dst = (y < 8 ? Qh : Kh) +
        ((size_t)head * N_TOK + n0 + l31) * 32 + 16 * hi;
    *(uint4*)dst = make_uint4(pk[0], pk[1], pk[2], pk[3]);
    *(uint4*)(dst + 8) = make_uint4(pk[4], pk[5], pk[6], pk[7]);
  } else {
    // V fragment: lane (ch=l31, ktile-half=hi) holds tokens hi*16..+15
    unsigned pk[8];
#pragma unroll
    for (int i = 0; i < 8; i++)
      pk[i] = pkbf(ldsT[wave][16 * hi + 2 * i][l31],
                   ldsT[wave][16 * hi + 2 * i + 1][l31]);
    unsigned short* dst = Vf +
        (((size_t)head * 256 + (n0 >> 4) + hi) * 32 + l31) * 16;
    *(uint4*)dst = make_uint4(pk[0], pk[1], pk[2], pk[3]);
    *(uint4*)(dst + 8) = make_uint4(pk[4], pk[5], pk[6], pk[7]);
  }
}

// ---------------------------------------------------------------------------
// Flash attention: swapped-QK^T 32x32x16, per-head coalesced layouts,
// explicit 1-tile register prefetch, exp2 (gate*scale*log2e folded in Q),
// no max tracking (scores O(0.5)). Partial O -> Ob [s][8][4096][32] bf16.
// ---------------------------------------------------------------------------
__global__ __launch_bounds__(256, 4) void attn_kernel(
    const unsigned short* __restrict__ Qh, const unsigned short* __restrict__ Kh,
    const unsigned short* __restrict__ Vf,
    unsigned short* __restrict__ Ob, float* __restrict__ ls, int kps)
{
  __shared__ float ldsT[4][32][33];
  const int tid = threadIdx.x;
  const int wave = tid >> 6, lane = tid & 63;
  const int l31 = lane & 31, hi = lane >> 5;
  const int hh = blockIdx.x >> 5;
  const int qb = blockIdx.x & 31;
  const int split = blockIdx.y;
  const int qrow0 = qb * 128 + wave * 32;
  const int kbase0 = split * kps;

  const unsigned short* qrow = Qh + ((size_t)hh * N_TOK + qrow0 + l31) * 32;
  const bf16x8 qf0 = *(const bf16x8*)(qrow + hi * 8);
  const bf16x8 qf1 = *(const bf16x8*)(qrow + 16 + hi * 8);

  const unsigned short* kb_base = Kh + (size_t)hh * (N_TOK * 32);
  const unsigned short* vf_base = Vf + (size_t)hh * (256 * 32 * 16);

  f32x16 acc, zero16;
#pragma unroll
  for (int i = 0; i < 16; i++) { acc[i] = 0.f; zero16[i] = 0.f; }
  float lsum = 0.f;

#define LK(kb, s) (*(const bf16x8*)(kb_base + (size_t)((kb) + l31) * 32 + (s) * 16 + hi * 8))
#define LV(kt2)   (*(const bf16x8*)(vf_base + (size_t)((kt2) * 32 + l31) * 16 + hi * 8))

  bf16x8 kf0 = LK(kbase0, 0), kf1 = LK(kbase0, 1);
  bf16x8 vb0 = LV(kbase0 >> 4), vb1 = LV((kbase0 >> 4) + 1);

#pragma unroll 2
  for (int kt = 0; kt < kps; kt += 32) {
    const int nxt = (kt + 32 < kps) ? (kbase0 + kt + 32) : kbase0;
    bf16x8 nk0 = LK(nxt, 0), nk1 = LK(nxt, 1);
    bf16x8 nv0 = LV(nxt >> 4), nv1 = LV((nxt >> 4) + 1);

    f32x16 s = __builtin_amdgcn_mfma_f32_32x32x16_bf16(kf0, qf0, zero16, 0, 0, 0);
    s = __builtin_amdgcn_mfma_f32_32x32x16_bf16(kf1, qf1, s, 0, 0, 0);

    float p[16];
#pragma unroll
    for (int r = 0; r < 16; r++) p[r] = fexp2(s[r]);

    lsum += (((p[0] + p[1]) + (p[2] + p[3])) + ((p[4] + p[5]) + (p[6] + p[7]))) +
            (((p[8] + p[9]) + (p[10] + p[11])) + ((p[12] + p[13]) + (p[14] + p[15])));

    unsigned a0 = pkbf(p[0], p[1]),   a1 = pkbf(p[2], p[3]);
    unsigned b0 = pkbf(p[4], p[5]),   b1 = pkbf(p[6], p[7]);
    unsigned c0 = pkbf(p[8], p[9]),   c1 = pkbf(p[10], p[11]);
    unsigned d0 = pkbf(p[12], p[13]), d1 = pkbf(p[14], p[15]);
    asm("v_permlane32_swap_b32 %0, %1" : "+v"(a0), "+v"(b0));
    asm("v_permlane32_swap_b32 %0, %1" : "+v"(a1), "+v"(b1));
    asm("v_permlane32_swap_b32 %0, %1" : "+v"(c0), "+v"(d0));
    asm("v_permlane32_swap_b32 %0, %1" : "+v"(c1), "+v"(d1));
    union { unsigned w[4]; bf16x8 v; } u0, u1;
    u0.w[0] = a0; u0.w[1] = a1; u0.w[2] = b0; u0.w[3] = b1;
    u1.w[0] = c0; u1.w[1] = c1; u1.w[2] = d0; u1.w[3] = d1;

    acc = __builtin_amdgcn_mfma_f32_32x32x16_bf16(u0.v, vb0, acc, 0, 0, 0);
    acc = __builtin_amdgcn_mfma_f32_32x32x16_bf16(u1.v, vb1, acc, 0, 0, 0);

    kf0 = nk0; kf1 = nk1; vb0 = nv0; vb1 = nv1;
  }
#undef LK
#undef LV

  float lt = lsum + __shfl_xor(lsum, 32);
  if (hi == 0)
    ls[((size_t)split * 8 + hh) * N_TOK + qrow0 + l31] = lt;

  // epilogue transpose: acc[r] = O[q=qrow0+crow(r,hi)][vch=l31]
#pragma unroll
  for (int r = 0; r < 16; r++)
    ldsT[wave][(r & 3) + 8 * (r >> 2) + 4 * hi][l31] = acc[r];
  unsigned pk[8];
#pragma unroll
  for (int i = 0; i < 8; i++)
    pk[i] = pkbf(ldsT[wave][l31][16 * hi + 2 * i],
                 ldsT[wave][l31][16 * hi + 2 * i + 1]);
  unsigned short* dst =
      Ob + (((size_t)split * 8 + hh) * N_TOK + qrow0 + l31) * 32 + 16 * hi;
  *(uint4*)dst = make_uint4(pk[0], pk[1], pk[2], pk[3]);
  *(uint4*)(dst + 8) = make_uint4(pk[4], pk[5], pk[6], pk[7]);
}

// ---------------------------------------------------------------------------
// Combine splits + normalize -> Ab[n][256] bf16.
// ---------------------------------------------------------------------------
__global__ __launch_bounds__(256) void reduce_kernel(
    const unsigned short* __restrict__ Ob, const float* __restrict__ ls,
    unsigned short* __restrict__ Ab, int ksplit)
{
  int gid = blockIdx.x * 256 + threadIdx.x;   // 131072
  int n = gid >> 5, c8 = (gid & 31) * 8;
  int hh = c8 >> 5, cc = c8 & 31;
  float o[8];
#pragma unroll
  for (int i = 0; i < 8; i++) o[i] = 0.f;
  float l = 0.f;
  for (int s = 0; s < ksplit; s++) {
    uint4 raw = *(const uint4*)(Ob + (((size_t)s * 8 + hh) * N_TOK + n) * 32 + cc);
    unsigned w[4] = {raw.x, raw.y, raw.z, raw.w};
#pragma unroll
    for (int i = 0; i < 4; i++) {
      o[2 * i]     += __uint_as_float(w[i] << 16);
      o[2 * i + 1] += __uint_as_float(w[i] & 0xffff0000u);
    }
    l += ls[((size_t)s * 8 + hh) * N_TOK + n];
  }
  float inv = 1.f / l;
  unsigned pk[4];
#pragma unroll
  for (int i = 0; i < 4; i++)
    pk[i] = pkbf(o[2 * i] * inv, o[2 * i + 1] * inv);
  *(uint4*)(Ab + (size_t)n * CT + c8) = make_uint4(pk[0], pk[1], pk[2], pk[3]);
}

// ---------------------------------------------------------------------------
// Output projection: d_out[o][n] = Ab[n][:] . Wp[o][:] + bp[o], f32 col-major.
// ---------------------------------------------------------------------------
__global__ __launch_bounds__(256) void pout_kernel(
    const unsigned short* __restrict__ Ab, const unsigned short* __restrict__ Wall,
    const float* __restrict__ bp, float* __restrict__ out)
{
  const int tid = threadIdx.x;
  const int wave = tid >> 6, lane = tid & 63;
  const int l31 = lane & 31, hi = lane >> 5;
  const int n0 = blockIdx.x * 128 + wave * 32;
  const int o0 = blockIdx.y * 32;

  f32x16 accE, accO;
#pragma unroll
  for (int i = 0; i < 16; i++) { accE[i] = 0.f; accO[i] = 0.f; }
  gemm_tile<256>(Ab + (size_t)(n0 + l31) * 256 + hi * 8,
                 Wall + 131072 + (size_t)(o0 + l31) * 256 + hi * 8, accE, accO);
  const float bo = bp[o0 + l31];
#pragma unroll
  for (int rr = 0; rr < 4; rr++) {
    float4 w = make_float4(accE[4 * rr + 0] + accO[4 * rr + 0] + bo,
                           accE[4 * rr + 1] + accO[4 * rr + 1] + bo,
                           accE[4 * rr + 2] + accO[4 * rr + 2] + bo,
                           accE[4 * rr + 3] + accO[4 * rr + 3] + bo);
    *(float4*)(out + (size_t)(o0 + l31) * N_TOK + n0 + 8 * rr + 4 * hi) = w;
  }
}

// ---------------------------------------------------------------------------
extern "C" void kernel_launch(void* const* d_in, const int* in_sizes, int n_in,
                              void* d_out, int out_size, void* d_ws, size_t ws_size,
                              hipStream_t stream)
{
  const float* thermal = (const float*)d_in[0];
  const float* optical = (const float*)d_in[1];
  const float* em      = (const float*)d_in[2];
  const float* Wq = (const float*)d_in[3];
  const float* bq = (const float*)d_in[4];
  const float* Wk = (const float*)d_in[5];
  const float* bk = (const float*)d_in[6];
  const float* Wv = (const float*)d_in[7];
  const float* bv = (const float*)d_in[8];
  const float* w1 = (const float*)d_in[9];
  const float* b1 = (const float*)d_in[10];
  const float* w2 = (const float*)d_in[11];
  const float* b2 = (const float*)d_in[12];
  const float* Wp = (const float*)d_in[13];
  const float* bp = (const float*)d_in[14];

  char* ws = (char*)d_ws;
  const size_t MB = 1u << 20;
  unsigned short* Xbt = (unsigned short*)(ws);                  // 2MB
  unsigned short* Xbo = (unsigned short*)(ws + 2 * MB);         // 1MB
  unsigned short* Wall = (unsigned short*)(ws + 3 * MB);        // 384KB
  float* gbuf = (float*)(ws + 3 * MB + 512 * 1024);             // 128KB
  unsigned short* Qh = (unsigned short*)(ws + 4 * MB);          // 2MB
  unsigned short* Kh = (unsigned short*)(ws + 6 * MB);          // 2MB
  unsigned short* Vf = (unsigned short*)(ws + 8 * MB);          // 2MB
  unsigned short* Ab = (unsigned short*)(ws + 10 * MB);         // 2MB
  float* lsp = (float*)(ws + 12 * MB);                          // ksplit*128KB
  unsigned short* Ob = (unsigned short*)(ws + 13 * MB);         // ksplit*2MB

  const int ksplit = (ws_size >= 29 * MB) ? 8 : 4;

  prep_kernel<<<240, 256, 0, stream>>>(thermal, optical, Wq, Wk, Wv, Wp,
                                       em, w1, b1, w2, b2, Xbt, Xbo, Wall, gbuf);
  qkv_kernel<<<dim3(32, 24), 256, 0, stream>>>(Xbt, Xbo, Wall, bq, bk, bv, gbuf,
                                               Qh, Kh, Vf);
  attn_kernel<<<dim3(256, ksplit), 256, 0, stream>>>(Qh, Kh, Vf, Ob, lsp,
                                                     N_TOK / ksplit);
  reduce_kernel<<<512, 256, 0, stream>>>(Ob, lsp, Ab, ksplit);
  pout_kernel<<<dim3(32, 8), 256, 0, stream>>>(Ab, Wall, bp, (float*)d_out);
}